// Round 8
// baseline (1585.393 us; speedup 1.0000x reference)
//
#include <hip/hip_runtime.h>
#include <math.h>

// ---------------------------------------------------------------------------
// HFPS: CNN (4 residual blocks, circular 3x3 conv, 48x48, 64ch) ->
//       A = [[Fvv[n][:,n], Fvh_n],[-Fvh_n^T, Fhh_a]] (1048x1048 skew) ->
//       sign(Pf(A)), log|Pf(A)| + log_J
// Pfaffian via unpivoted blocked skew LDL^T with 2x2 pivots, fp64.
//   Pf = prod(t_p); log|Pf| = sum log|t_p| = 0.5*slogdet(A).
//
// R8 changes (R7 post-mortem: traffic prediction matched (55/13 MB) but the
// 64-lane x 4-load barrier poll herd (~65k agent loads/round on 16 lines)
// taxes every wait ~8-10us and congests the fabric for the phases):
//   1. tree barrier: monotone group counters (8x32) -> root counter -> root
//      epoch; ONE lane polls ONE line with s_sleep(8). Fence-free (R5).
//   2. Pk stored TRANSPOSED as [32][m] (a,b)-pairs -> phase-T reads are
//      coalesced 16B/lane; publication is scattered bypass stores.
//   3. diag tile published at START of T (T-a) + per-panel 64-arrival
//      counter replaces the 2nd barrier -> next D overlaps straggler T-b.
//      Phase D: 1 syncthreads/step, divide pipelined one step ahead.
//
// Workspace layout:
//   0:     tree barrier (group ctrs 16*g, root ctr [128], root ep [144])
//   768:   dctr[32] (diag-ready arrival counters, u32)
//   1024:  logJ accumulator (double)
//   1088:  nidx[1024] (int)
//   8192:  tbuf / ybuf / hbuf0 / hbuf1 (4 x 64*2304 fp32)
//   2367488: Pk panel buffers (<=4,128,768 B)
//   6496256: Dk diag buffers (17*64*64*8 = 557,056 B)
// ---------------------------------------------------------------------------

#define NPIX 2304          // 48*48
#define MSZ  4608          // 2*48*48
#define NOCC 1024
#define NHID 24
#define PF_N 1048          // NOCC + 2*NHID
#define PF_BLOCKS 256
#define NPAN 17            // 16 panels of 64 + final 24

__device__ __forceinline__ float gelu_f(float v){
  // jax.nn.gelu approximate=True (tanh form)
  float v3 = v*v*v;
  return 0.5f*v*(1.0f + tanhf(0.7978845608028654f*(v + 0.044715f*v3)));
}

// coherent (cache-bypassing) accessors: relaxed agent-scope atomics (R5).
__device__ __forceinline__ double ald(const double* p){
  return __hip_atomic_load(p, __ATOMIC_RELAXED, __HIP_MEMORY_SCOPE_AGENT);
}
__device__ __forceinline__ void ast(double* p, double v){
  __hip_atomic_store(p, v, __ATOMIC_RELAXED, __HIP_MEMORY_SCOPE_AGENT);
}

// ---- occupied-site indices (sorted), x[i]==1.0f exactly ----
__global__ void k_find_n(const float* __restrict__ x, int* __restrict__ nidx){
  __shared__ int cnt[256];
  __shared__ int off[256];
  int t = threadIdx.x;
  int c = 0;
  for (int k = 0; k < 18; k++) c += (x[t*18+k] == 1.0f) ? 1 : 0;
  cnt[t] = c;
  __syncthreads();
  if (t == 0){ int s = 0; for (int q=0;q<256;q++){ off[q]=s; s+=cnt[q]; } }
  __syncthreads();
  int o = off[t];
  for (int k = 0; k < 18; k++){
    int idx = t*18+k;
    if (x[idx] == 1.0f) nidx[o++] = idx;
  }
}

// ---- elementwise pre-op: t = [gelu](h*scale) ----
__global__ void k_pre(const float* __restrict__ in, float* __restrict__ outp,
                      int count, int dogelu, float scale){
  int g = blockIdx.x*256 + threadIdx.x;
  if (g >= count) return;
  float v = in[g]*scale;
  if (dogelu) v = gelu_f(v);
  outp[g] = v;
}

// ---- circular 3x3 conv, 64 out channels, fused bias/gelu/residual/scale ----
__global__ __launch_bounds__(256) void k_conv(const float* __restrict__ in,
      const float* __restrict__ wgt, const float* __restrict__ bias,
      const float* __restrict__ res, float* __restrict__ outp,
      int cin, int resmode, int dogelu, float scale){
  int c = blockIdx.x / 9;
  int p = (blockIdx.x % 9)*256 + threadIdx.x;
  int y = p / 48, x = p - y*48;
  int ym = ((y+47)%48)*48, y0 = y*48, yp = ((y+1)%48)*48;
  int xm = (x+47)%48, xq = (x+1)%48;
  float s = 0.f;
  const float* wp = wgt + c*cin*9;
  for (int ci = 0; ci < cin; ci++){
    const float* b_ = in + ci*NPIX;
    s += b_[ym+xm]*wp[0] + b_[ym+x]*wp[1] + b_[ym+xq]*wp[2]
       + b_[y0+xm]*wp[3] + b_[y0+x]*wp[4] + b_[y0+xq]*wp[5]
       + b_[yp+xm]*wp[6] + b_[yp+x]*wp[7] + b_[yp+xq]*wp[8];
    wp += 9;
  }
  if (bias) s += bias[c];
  if (dogelu) s = gelu_f(s);
  if (resmode == 1) s += res[c*NPIX + p];
  else if (resmode == 2) s += res[(c>>5)*NPIX + p];  // jnp.repeat(res,32,axis=0)
  s *= scale;
  outp[c*NPIX + p] = s;
}

// ---- log_J = sum over channels 48..63 of final h ----
__global__ void k_logJ(const float* __restrict__ hfin, double* __restrict__ acc){
  int g = blockIdx.x*256 + threadIdx.x;   // 144*256 = 36864
  double v = (double)hfin[48*NPIX + g];
  for (int o = 32; o > 0; o >>= 1) v += __shfl_down(v, o, 64);
  __shared__ double wsum[4];
  int lane = threadIdx.x & 63, wv = threadIdx.x >> 6;
  if (lane == 0) wsum[wv] = v;
  __syncthreads();
  if (threadIdx.x == 0) atomicAdd(acc, wsum[0]+wsum[1]+wsum[2]+wsum[3]);
}

// ---- fence-free TREE grid barrier: monotone counters, 1-lane 1-line poll ----
// arrival: group ctr (32/group, 8 padded lines) -> root ctr -> root epoch.
// __syncthreads drains vmcnt before arrival (data visible at coherence point).
__device__ __forceinline__ void gridbar(unsigned* bar, unsigned ep){
  __syncthreads();
  if (threadIdx.x == 0){
    asm volatile("" ::: "memory");
    __builtin_amdgcn_s_waitcnt(0);
    const int g = blockIdx.x >> 5;
    unsigned a = __hip_atomic_fetch_add(&bar[16*g], 1u, __ATOMIC_RELAXED,
                                        __HIP_MEMORY_SCOPE_AGENT);
    if (a == ep*32u - 1u){
      unsigned r = __hip_atomic_fetch_add(&bar[128], 1u, __ATOMIC_RELAXED,
                                          __HIP_MEMORY_SCOPE_AGENT);
      if (r == ep*8u - 1u)
        __hip_atomic_store(&bar[144], ep, __ATOMIC_RELAXED,
                           __HIP_MEMORY_SCOPE_AGENT);
    }
    while (__hip_atomic_load(&bar[144], __ATOMIC_RELAXED,
                             __HIP_MEMORY_SCOPE_AGENT) < ep)
      __builtin_amdgcn_s_sleep(8);
    asm volatile("" ::: "memory");
  }
  __syncthreads();
}

// Pk offset in doubles: 64 * sum_{k'<k} (984 - 64k')
__device__ __forceinline__ size_t pk_off(int k){
  return (size_t)64 * ((size_t)984*(size_t)k - (size_t)32*(size_t)k*(size_t)(k-1));
}

// ---- distributed-A blocked skew LDL^T (2x2 pivots, BK=64) ----
// Block b owns rows {b, b+256, b+512, b+768} (+ b+1024 if b<24) in LDS.
__global__ __launch_bounds__(256) void k_pf(
      const float* __restrict__ Fvv, const float* __restrict__ Fhh,
      const float* __restrict__ hfin, const int* __restrict__ nidx_g,
      double* __restrict__ Pbase, double* __restrict__ Dbase,
      unsigned* __restrict__ bar, unsigned* __restrict__ dctr,
      const double* __restrict__ logJ, float* __restrict__ outp){
  const int N = PF_N;
  const int tid = threadIdx.x;
  const int b = blockIdx.x;
  const int nrows = (b < 24) ? 5 : 4;

  __shared__ double rowbuf[2688];   // owned rows, cols 0..i-1 packed
  __shared__ double sAAf[32][64];   // colA * invt history (for R)
  __shared__ double sBBf[32][64];   // colB * invt history
  __shared__ double colA[2][64], colB[2][64];   // double-buffered pivot cols
  __shared__ double sInv[32], sTv[32];
  __shared__ double sCA[5][32], sCB[5][32];
  __shared__ int    snidx[1024];

  #define RIDX(s)  (b + 256*(s))
  #define ROFF(s)  ((s)*b + 128*(s)*((s)-1))

  for (int q = tid; q < 1024; q += 256) snidx[q] = nidx_g[q];
  __syncthreads();

  // ---- gather own rows straight from inputs (no global A) ----
  for (int s = 0; s < nrows; s++){
    const int i = RIDX(s);
    const int o = ROFF(s);
    if (i < NOCC){
      const int ni = snidx[i];
      const float* rowF = Fvv + (size_t)ni*MSZ;
      for (int j = tid; j < i; j += 256){
        int nj = snidx[j];
        rowbuf[o+j] = 0.5*((double)rowF[nj] - (double)Fvv[(size_t)nj*MSZ + ni]);
      }
    } else {
      const int r = i - NOCC;
      for (int j = tid; j < i; j += 256){
        double v;
        if (j < NOCC){
          int nj = snidx[j];
          int ss = (nj >= NPIX) ? 1 : 0;
          v = -(double)hfin[(2*r+ss)*NPIX + (nj - ss*NPIX)];
        } else {
          int r2 = j - NOCC;
          v = 0.5*((double)Fhh[r*NHID+r2] - (double)Fhh[r2*NHID+r]);
        }
        rowbuf[o+j] = v;
      }
    }
  }
  __syncthreads();

  // ---- publish diag tile 0 (rows 0..63 owned by blocks 0..63, s=0) ----
  if (b < 64){
    for (int c = tid; c < b; c += 256)
      ast(&Dbase[(size_t)b*64 + c], rowbuf[c]);
  }
  unsigned ep = 0;
  gridbar(bar, ++ep);

  double lsum = 0.0, lsgn = 1.0;   // block 0 / thread 0

  for (int k = 0; k < NPAN; k++){
    const int c0  = 64*k;
    const int w   = (N - c0 < 64) ? (N - c0) : 64;
    const int np  = w >> 1;
    const int tc0 = c0 + w;
    const int m   = N - tc0;
    const double* Dk = Dbase + (size_t)k*4096;
    double* PkT = Pbase + pk_off(k);

    // ---- wait for diag tile k (published in T-a of panel k-1) ----
    if (k > 0){
      if (tid == 0){
        asm volatile("" ::: "memory");
        while (__hip_atomic_load(&dctr[k], __ATOMIC_RELAXED,
                                 __HIP_MEMORY_SCOPE_AGENT) < (unsigned)w)
          __builtin_amdgcn_s_sleep(4);
        asm volatile("" ::: "memory");
      }
      __syncthreads();
    }

    // ---------------- phase D: register-tile factorization, 1 sync/step ----
    {
      const int ty = tid >> 4, tx = tid & 15;
      double T4[4][4];
      #pragma unroll
      for (int q = 0; q < 4; q++)
        #pragma unroll
        for (int p = 0; p < 4; p++){
          int r = 4*ty+q, c = 4*tx+p;
          double v = 0.0;
          if (r < w && c < w){
            if (r > c) v = Dk[r*64+c];
            else if (r < c) v = -Dk[c*64+r];
          }
          T4[q][p] = v;
        }
      if (tx == 0){
        #pragma unroll
        for (int q = 0; q < 4; q++){
          colA[0][4*ty+q] = T4[q][0];
          colB[0][4*ty+q] = T4[q][1];
        }
      }
      if (tid == 0){ double t0 = T4[0][1]; sTv[0] = t0; sInv[0] = 1.0/t0; }
      __syncthreads();
      for (int j = 0; j < np; j++){
        const int pb = j & 1, nb = pb ^ 1;
        const double invt = sInv[j];
        if (tid < 64){
          sAAf[j][tid] = colA[pb][tid]*invt;
          sBBf[j][tid] = colB[pb][tid]*invt;
        }
        const int r2 = 2*j + 2;
        const bool pub = (j+1 < np) && (tx == (r2 >> 2));
        const int p0 = r2 & 3;
        #pragma unroll
        for (int q = 0; q < 4; q++){
          const int r = 4*ty + q;
          if (r >= r2){
            const double ar = colA[pb][r], br = colB[pb][r];
            #pragma unroll
            for (int p = 0; p < 4; p++){
              const int c = 4*tx + p;
              if (c >= r2) T4[q][p] += (br*colA[pb][c] - ar*colB[pb][c]) * invt;
            }
          }
          if (pub){ colA[nb][r] = T4[q][p0]; colB[nb][r] = T4[q][p0+1]; }
        }
        if (j+1 < np && ty == (r2 >> 2) && tx == (r2 >> 2)){
          // owner of updated element (r2, r2+1): pipeline next divide
          const double t = T4[r2 & 3][(r2+1) & 3];
          sTv[j+1] = t; sInv[j+1] = 1.0/t;
        }
        __syncthreads();
      }
      if (b == 0 && tid < 64){
        double lv = 0.0; int sg = 0;
        if (tid < np){ double t = sTv[tid]; lv = log(fabs(t)); sg = (t<0.0)?1:0; }
        for (int o = 32; o > 0; o >>= 1){
          lv += __shfl_down(lv, o, 64);
          sg += __shfl_down(sg, o, 64);
        }
        if (tid == 0){ lsum += lv; if (sg & 1) lsgn = -lsgn; }
      }
    }

    // ---------------- phase R: own rows' panel cols + transposed Pk publish --
    if (m > 0){               // m>0 implies w==64, np==32
      const int wv = tid >> 6, lc = tid & 63;
      for (int s = wv; s < nrows; s += 4){
        const int i = RIDX(s);
        if (i < tc0) continue;
        const int o = ROFF(s);
        double v = rowbuf[o + c0 + lc];
        #pragma unroll 8
        for (int j = 0; j < 32; j++){
          double a  = __shfl(v, 2*j,   64);
          double bb = __shfl(v, 2*j+1, 64);
          if (lc >= 2*j+2) v += bb*sAAf[j][lc] - a*sBBf[j][lc];
        }
        rowbuf[o + c0 + lc] = v;
        double vb = __shfl(v, lc|1, 64);
        if ((lc & 1) == 0){
          size_t off = (size_t)(lc>>1)*2*(size_t)m + 2*(size_t)(i - tc0);
          ast(&PkT[off],   v);
          ast(&PkT[off+1], vb);
        }
      }
      __syncthreads();
      {
        const int s = tid >> 5, l = tid & 31;
        if (tid < 160 && s < nrows){
          const int i = RIDX(s);
          if (i >= tc0){
            const int o = ROFF(s);
            sCA[s][l] = rowbuf[o + c0 + 2*l    ] * sInv[l];
            sCB[s][l] = rowbuf[o + c0 + 2*l + 1] * sInv[l];
          }
        }
      }
      gridbar(bar, ++ep);
    }

    // ---------------- phase T ----------------
    if (m > 0){
      const int wn = (m < 64) ? m : 64;   // next diag width
      int sdiag = -1;
      for (int s = 0; s < nrows; s++){
        int i = RIDX(s);
        if (i >= tc0 && i < tc0 + wn) sdiag = s;
      }
      // T-a: update own diag-tile row, publish to D(k+1), signal dctr
      if (sdiag >= 0){
        const int i_d = RIDX(sdiag), o_d = ROFF(sdiag);
        const int len = i_d - tc0;         // 0..wn-1
        if (tid < len){
          const double* pc = PkT + 2*tid;
          double acc = rowbuf[o_d + tc0 + tid];
          #pragma unroll 8
          for (int l = 0; l < 32; l++){
            double a  = pc[(size_t)l*2*(size_t)m];
            double bb = pc[(size_t)l*2*(size_t)m + 1];
            acc += sCB[sdiag][l]*a - sCA[sdiag][l]*bb;
          }
          rowbuf[o_d + tc0 + tid] = acc;
        }
        __syncthreads();
        double* Dn = Dbase + (size_t)(k+1)*4096 + (size_t)len*64;
        for (int c = tid; c < len; c += 256)
          ast(&Dn[c], rowbuf[o_d + tc0 + c]);
        __syncthreads();               // drains vmcnt per wave
        if (tid == 0){
          asm volatile("" ::: "memory");
          __builtin_amdgcn_s_waitcnt(0);
          __hip_atomic_fetch_add(&dctr[k+1], 1u, __ATOMIC_RELAXED,
                                 __HIP_MEMORY_SCOPE_AGENT);
        }
      }
      // T-b: remaining own rows, coalesced transposed-Pk reads
      int jmax = 0;
      for (int s = 0; s < nrows; s++){
        int i = RIDX(s);
        if (s != sdiag && i > jmax) jmax = i;
      }
      for (int base = tc0; base < jmax; base += 256){
        const int j = base + tid;
        const bool jv = (j < jmax);
        double acc[5];
        #pragma unroll
        for (int s = 0; s < 5; s++)
          acc[s] = (s < nrows && s != sdiag && jv && j < RIDX(s))
                 ? rowbuf[ROFF(s)+j] : 0.0;
        if (jv){
          const double* pc = PkT + 2*(j - tc0);
          #pragma unroll 4
          for (int l = 0; l < 32; l++){
            const double a  = pc[(size_t)l*2*(size_t)m];
            const double bb = pc[(size_t)l*2*(size_t)m + 1];
            #pragma unroll
            for (int s = 0; s < 5; s++)
              acc[s] += sCB[s][l]*a - sCA[s][l]*bb;
          }
          #pragma unroll
          for (int s = 0; s < 5; s++)
            if (s < nrows && s != sdiag && j < RIDX(s)) rowbuf[ROFF(s)+j] = acc[s];
        }
      }
      // next panel's dctr-wait __syncthreads orders rowbuf for phase R
    }
  }

  if (b == 0 && tid == 0){
    outp[0] = (float)lsgn;
    outp[1] = (float)(lsum + logJ[0]);
  }
  #undef RIDX
  #undef ROFF
}

// ---------------------------------------------------------------------------
extern "C" void kernel_launch(void* const* d_in, const int* in_sizes, int n_in,
                              void* d_out, int out_size, void* d_ws, size_t ws_size,
                              hipStream_t stream){
  (void)in_sizes; (void)n_in; (void)out_size; (void)ws_size;
  const float* x   = (const float*)d_in[0];
  const float* Fvv = (const float*)d_in[1];
  const float* Fhh = (const float*)d_in[2];
  const float* w1[4] = {(const float*)d_in[3], (const float*)d_in[7],
                        (const float*)d_in[11], (const float*)d_in[15]};
  const float* b1[4] = {(const float*)d_in[4], (const float*)d_in[8],
                        (const float*)d_in[12], (const float*)d_in[16]};
  const float* w2[4] = {(const float*)d_in[5], (const float*)d_in[9],
                        (const float*)d_in[13], (const float*)d_in[17]};
  const float* b2[3] = {(const float*)d_in[6], (const float*)d_in[10],
                        (const float*)d_in[14]};

  char* ws = (char*)d_ws;
  unsigned* bar   = (unsigned*)(ws + 0);        // tree barrier, 0..640
  unsigned* dctr  = (unsigned*)(ws + 768);      // 32 u32
  double* logJa   = (double*)(ws + 1024);
  int*    nidx    = (int*)(ws + 1088);          // 4 KB
  const size_t CB = 589824;  // 64*2304*4
  float* tbuf  = (float*)(ws + 8192);
  float* ybuf  = (float*)(ws + 8192 + CB);
  float* hbuf0 = (float*)(ws + 8192 + 2*CB);
  float* hbuf1 = (float*)(ws + 8192 + 3*CB);
  double* Pbase = (double*)(ws + 8192 + 4*CB);            // 2,367,488
  double* Dbase = (double*)(ws + 8192 + 4*CB + 4128768);  // 6,496,256

  hipMemsetAsync(d_ws, 0, 2048, stream);        // barrier + dctr + logJ acc
  k_find_n<<<1,256,0,stream>>>(x, nidx);

  // CNN block 0: t = (h/sqrt(1))/sqrt(2); res repeats 2ch -> 64ch
  k_pre <<<18, 256,0,stream>>>(x, tbuf, 4608, 0, 0.70710678118654752f);
  k_conv<<<576,256,0,stream>>>(tbuf, w1[0], b1[0], nullptr, ybuf, 2, 0, 1, 1.0f);
  k_conv<<<576,256,0,stream>>>(ybuf, w2[0], b2[0], x,      hbuf0, 64, 2, 0, 1.0f);
  // block 1
  k_pre <<<576,256,0,stream>>>(hbuf0, tbuf, 147456, 1, 0.70710678118654752f);
  k_conv<<<576,256,0,stream>>>(tbuf, w1[1], b1[1], nullptr, ybuf, 64, 0, 1, 1.0f);
  k_conv<<<576,256,0,stream>>>(ybuf, w2[1], b2[1], hbuf0,  hbuf1, 64, 1, 0, 1.0f);
  // block 2
  k_pre <<<576,256,0,stream>>>(hbuf1, tbuf, 147456, 1, 0.57735026918962576f);
  k_conv<<<576,256,0,stream>>>(tbuf, w1[2], b1[2], nullptr, ybuf, 64, 0, 1, 1.0f);
  k_conv<<<576,256,0,stream>>>(ybuf, w2[2], b2[2], hbuf1,  hbuf0, 64, 1, 0, 1.0f);
  // block 3 (no b2; fold final 1/sqrt(5) into epilogue)
  k_pre <<<576,256,0,stream>>>(hbuf0, tbuf, 147456, 1, 0.5f);
  k_conv<<<576,256,0,stream>>>(tbuf, w1[3], b1[3], nullptr, ybuf, 64, 0, 1, 1.0f);
  k_conv<<<576,256,0,stream>>>(ybuf, w2[3], nullptr, hbuf0, hbuf1, 64, 1, 0,
                               0.44721359549995794f);

  k_logJ<<<144,256,0,stream>>>(hbuf1, logJa);
  k_pf  <<<PF_BLOCKS,256,0,stream>>>(Fvv, Fhh, hbuf1, nidx,
                                     Pbase, Dbase, bar, dctr, logJa,
                                     (float*)d_out);
}